// Round 10
// baseline (425.817 us; speedup 1.0000x reference)
//
#include <hip/hip_runtime.h>
#include <math.h>

// NanoRAG: cosine-sim retrieval + top-8 + softmax fusion.
// Two-phase: approximate bf16-hi scoring over a LINEARIZED doc plane, then
// exact fp32 rescore of 256 candidates/query.
//  K0 qprep:  normalize queries -> qn fp32 + A-fragment-layout bf16 (qhf)
//  K1 conv:   docs fp32 (linear m13-pattern read) -> tiled bf16-hi plane T
//             (201 MB; B-fragments byte-linear per wave). LDS transpose so
//             BOTH global read and write are wave-contiguous.
//  K2 score:  hi-only MFMA GEMM; wave reads ONE contiguous 24-KB stream.
//             Per-block(128 docs) top-8 lists -> pscore/pidx [q][2048][8].
//  K3 rescore: per query: 16 chunks x approx-top-16 = 256 candidates,
//             exact fp32 rescore + top-8 + softmax + fused -> d_out.
//
// d_out layout (fp32): fused[64*384], scores[64*8], idx[64*8]

#define EMBED 384
#define NDOCS 262144
#define BATCH 64
#define TOPK 8
#define NBLK 2048             // 128-doc blocks in score pass
#define EPSN 1e-8f
#define SCW 132

typedef __attribute__((ext_vector_type(8))) short bf16x8;
typedef __attribute__((ext_vector_type(4))) float f32x4;

// sorted top-8 insertion (desc score, asc idx on ties)
#define INS8(s_, i_) do {                                                     \
    if ((s_) > ts[7] || ((s_) == ts[7] && (i_) < ti[7])) {                    \
        ts[7] = (s_); ti[7] = (i_);                                           \
        _Pragma("unroll")                                                     \
        for (int r_ = 7; r_ > 0; --r_) {                                      \
            bool sw_ = (ts[r_] > ts[r_-1]) ||                                 \
                       (ts[r_] == ts[r_-1] && ti[r_] < ti[r_-1]);             \
            float a_ = ts[r_-1]; int b_ = ti[r_-1];                           \
            ts[r_-1] = sw_ ? ts[r_] : a_;  ti[r_-1] = sw_ ? ti[r_] : b_;      \
            ts[r_]   = sw_ ? a_ : ts[r_];  ti[r_]   = sw_ ? b_ : ti[r_];      \
        }                                                                     \
    }                                                                         \
} while (0)

// sorted top-16 insertion
#define INS16(s_, i_) do {                                                    \
    if ((s_) > ts[15] || ((s_) == ts[15] && (i_) < ti[15])) {                 \
        ts[15] = (s_); ti[15] = (i_);                                         \
        _Pragma("unroll")                                                     \
        for (int r_ = 15; r_ > 0; --r_) {                                     \
            bool sw_ = (ts[r_] > ts[r_-1]) ||                                 \
                       (ts[r_] == ts[r_-1] && ti[r_] < ti[r_-1]);             \
            float a_ = ts[r_-1]; int b_ = ti[r_-1];                           \
            ts[r_-1] = sw_ ? ts[r_] : a_;  ti[r_-1] = sw_ ? ti[r_] : b_;      \
            ts[r_]   = sw_ ? a_ : ts[r_];  ti[r_]   = sw_ ? b_ : ti[r_];      \
        }                                                                     \
    }                                                                         \
} while (0)

// RNE fp32 -> bf16 (manual; proven numerics R2-R8)
__device__ __forceinline__ unsigned rne1(float f) {
    unsigned u = __float_as_uint(f);
    return (u + 0x7fffu + ((u >> 16) & 1u)) >> 16;
}

// ---------------- K0: query prep ----------------
__global__ void qprep_kernel(const float* __restrict__ q,
                             float* __restrict__ qn,
                             unsigned short* __restrict__ qhf) {
    const int row = blockIdx.x;     // 64
    const int lane = threadIdx.x;   // 64
    float v[6];
    float s = 0.f;
#pragma unroll
    for (int i = 0; i < 6; ++i) {
        v[i] = q[row * EMBED + lane + 64 * i];
        s = fmaf(v[i], v[i], s);
    }
#pragma unroll
    for (int off = 32; off > 0; off >>= 1) s += __shfl_xor(s, off);
    float rinv = 1.0f / (sqrtf(s) + EPSN);
#pragma unroll
    for (int i = 0; i < 6; ++i) {
        int k = lane + 64 * i;
        float f = v[i] * rinv;
        qn[row * EMBED + k] = f;
        // A-fragment layout: lane l holds A[row=l&15][k=(l>>4)*8 ..+8]
        qhf[(row >> 4) * 6144 + (k >> 5) * 512 + ((k >> 3) & 3) * 128
            + (row & 15) * 8 + (k & 7)] = (unsigned short)rne1(f);
    }
}

// ---------------- K1: doc conversion (THE linearity experiment) ----------
// Panel = 32 docs. T layout per panel (24576 B):
//   byte = kb*2048 + (dd>>4)*1024 + kq*256 + (dd&15)*16 + half*8
//   holds doc dd (0..31), k = kb*32 + kq*8 + half*4 .. +3  (4 bf16 = 8 B)
// => score-pass lane l reads 16 B at kb*2048 + ht*1024 + l*16  (B-fragment).
__global__ __launch_bounds__(256) void conv_kernel(
        const float* __restrict__ docs, unsigned short* __restrict__ T) {
    __shared__ __align__(16) uint4 L4[1536];   // 24576 B
    uint2* L2p = (uint2*)L4;
    const int tid = threadIdx.x;

    for (int p4 = 0; p4 < 4; ++p4) {
        const int panel = blockIdx.x * 4 + p4;
        const float4* src = (const float4*)docs + (size_t)panel * 3072;
        if (p4) __syncthreads();               // prior writeout done
#pragma unroll
        for (int i = 0; i < 12; ++i) {
            int F = i * 256 + tid;             // 0..3071 within panel
            float4 v = src[F];                 // linear, 1KB/wave-instr
            int dd = (F * 10923) >> 20;        // F/96 (F<3072)
            int r4 = F - dd * 96;              // float4 index within row
            uint2 hv;
            hv.x = rne1(v.x) | (rne1(v.y) << 16);
            hv.y = rne1(v.z) | (rne1(v.w) << 16);
            unsigned byte_off = (unsigned)((r4 >> 3) * 2048 + (dd >> 4) * 1024
                              + ((r4 >> 1) & 3) * 256 + (dd & 15) * 16
                              + (r4 & 1) * 8);
            L2p[byte_off >> 3] = hv;
        }
        __syncthreads();
        uint4* dst = (uint4*)((char*)T + (size_t)panel * 24576);
#pragma unroll
        for (int j = 0; j < 6; ++j)
            dst[j * 256 + tid] = L4[j * 256 + tid];   // linear writes
    }
}

// ---------------- K2: approx score + per-block top-8 ----------------
__global__ __launch_bounds__(256, 4) void score_topk_kernel(
        const unsigned short* __restrict__ T,
        const unsigned short* __restrict__ qhf,
        float* __restrict__ pscore, int* __restrict__ pidx) {
    __shared__ float S[BATCH * SCW];           // 33792 B

    const int tid = threadIdx.x;
    const int l = tid & 63;
    const int w = tid >> 6;                    // wave -> 32-doc panel
    const int d0 = blockIdx.x * 128;

    const char* Tb = (const char*)T + (size_t)(blockIdx.x * 4 + w) * 24576 + l * 16;
    const char* Qb = (const char*)qhf + l * 16;

    f32x4 acc[2][4];
#pragma unroll
    for (int dt = 0; dt < 2; ++dt)
#pragma unroll
        for (int qt = 0; qt < 4; ++qt) acc[dt][qt] = (f32x4){0.f, 0.f, 0.f, 0.f};
    float sq0 = 0.f, sq1 = 0.f;

#pragma unroll
    for (int kb = 0; kb < 12; ++kb) {
        bf16x8 b0 = *(const bf16x8*)(Tb + kb * 2048);          // contiguous
        bf16x8 b1 = *(const bf16x8*)(Tb + kb * 2048 + 1024);   // stream/wave
#pragma unroll
        for (int e = 0; e < 8; ++e) {
            float f0 = __uint_as_float(((unsigned)(unsigned short)b0[e]) << 16);
            float f1 = __uint_as_float(((unsigned)(unsigned short)b1[e]) << 16);
            sq0 = fmaf(f0, f0, sq0);
            sq1 = fmaf(f1, f1, sq1);
        }
#pragma unroll
        for (int qt = 0; qt < 4; ++qt) {
            bf16x8 a = *(const bf16x8*)(Qb + qt * 12288 + kb * 1024);
            acc[0][qt] = __builtin_amdgcn_mfma_f32_16x16x32_bf16(a, b0, acc[0][qt], 0, 0, 0);
            acc[1][qt] = __builtin_amdgcn_mfma_f32_16x16x32_bf16(a, b1, acc[1][qt], 0, 0, 0);
        }
    }

    // approx doc norms: lanes l, l^16, l^32, l^48 hold k-quarters of doc l&15
    {
        float t0 = sq0;
        t0 += __shfl_xor(t0, 16);
        t0 += __shfl_xor(t0, 32);
        float rn0 = 1.0f / (sqrtf(t0) + EPSN);
        float t1 = sq1;
        t1 += __shfl_xor(t1, 16);
        t1 += __shfl_xor(t1, 32);
        float rn1 = 1.0f / (sqrtf(t1) + EPSN);
        const int q0 = (l >> 4) * 4;           // C/D: row=(lane>>4)*4+reg
        const int col0 = w * 32 + (l & 15);
        const int col1 = col0 + 16;
#pragma unroll
        for (int qt = 0; qt < 4; ++qt) {
            f32x4 a = acc[0][qt];
            S[(qt * 16 + q0 + 0) * SCW + col0] = a[0] * rn0;
            S[(qt * 16 + q0 + 1) * SCW + col0] = a[1] * rn0;
            S[(qt * 16 + q0 + 2) * SCW + col0] = a[2] * rn0;
            S[(qt * 16 + q0 + 3) * SCW + col0] = a[3] * rn0;
            f32x4 b = acc[1][qt];
            S[(qt * 16 + q0 + 0) * SCW + col1] = b[0] * rn1;
            S[(qt * 16 + q0 + 1) * SCW + col1] = b[1] * rn1;
            S[(qt * 16 + q0 + 2) * SCW + col1] = b[2] * rn1;
            S[(qt * 16 + q0 + 3) * SCW + col1] = b[3] * rn1;
        }
    }
    __syncthreads();

    // per-query top-8 over 128 docs (proven R3 epilogue)
    float ts[8]; int ti[8];
#pragma unroll
    for (int r = 0; r < 8; ++r) { ts[r] = -3.402823466e38f; ti[r] = 0x7fffffff; }
    const int sq_ = tid & 63, half = tid >> 6;
    if (tid < 128) {
        for (int ii = 0; ii < 64; ++ii) {
            int d = half * 64 + ((ii + sq_) & 63);
            float sc = S[sq_ * SCW + d];
            INS8(sc, d0 + d);
        }
    }
    __syncthreads();
    if (half == 1 && tid < 128) {
#pragma unroll
        for (int r = 0; r < 8; ++r) {
            S[sq_ * 8 + r] = ts[r];
            S[512 + sq_ * 8 + r] = __int_as_float(ti[r]);
        }
    }
    __syncthreads();
    if (tid < 64) {
#pragma unroll
        for (int r = 0; r < 8; ++r) {
            float s2 = S[sq_ * 8 + r];
            int i2 = __float_as_int(S[512 + sq_ * 8 + r]);
            INS8(s2, i2);
        }
        size_t o = ((size_t)sq_ * NBLK + blockIdx.x) * TOPK;
        *(float4*)&pscore[o]     = make_float4(ts[0], ts[1], ts[2], ts[3]);
        *(float4*)&pscore[o + 4] = make_float4(ts[4], ts[5], ts[6], ts[7]);
        *(int4*)&pidx[o]     = make_int4(ti[0], ti[1], ti[2], ti[3]);
        *(int4*)&pidx[o + 4] = make_int4(ti[4], ti[5], ti[6], ti[7]);
    }
}

// ---------------- K3: candidates + exact rescore + fuse ----------------
__global__ __launch_bounds__(256) void rescore_kernel(
        const float* __restrict__ docs, const float* __restrict__ qn,
        const float* __restrict__ pscore, const int* __restrict__ pidx,
        float* __restrict__ out) {
    const int q = blockIdx.x;
    const int tid = threadIdx.x;
    __shared__ float s1[4096];
    __shared__ int   i1[4096];
    __shared__ int   cand[256];
    __shared__ float cs2[256];
    __shared__ float cn2[256];
    __shared__ int   fi[TOPK];
    __shared__ float wr[TOPK];

    // phase 1: 16 chunks x 16 threads; thread scans 64 entries -> top-16
    {
        float ts[16]; int ti[16];
#pragma unroll
        for (int r = 0; r < 16; ++r) { ts[r] = -3.402823466e38f; ti[r] = 0x7fffffff; }
        const int c = tid >> 4, j = tid & 15;
        const float* sp = pscore + (size_t)q * 16384 + c * 1024 + j;
        const int*   ip = pidx   + (size_t)q * 16384 + c * 1024 + j;
        for (int ii = 0; ii < 64; ++ii) {
            float s = sp[ii * 16];
            if (s > ts[15] || (s == ts[15])) {
                int gi = ip[ii * 16];
                INS16(s, gi);
            }
        }
#pragma unroll
        for (int r = 0; r < 16; ++r) { s1[tid * 16 + r] = ts[r]; i1[tid * 16 + r] = ti[r]; }
    }
    __syncthreads();

    // phase 2: one thread per chunk merges its 16 sorted lists -> top-16
    if (tid < 16) {
        float ts[16]; int ti[16];
#pragma unroll
        for (int r = 0; r < 16; ++r) { ts[r] = -3.402823466e38f; ti[r] = 0x7fffffff; }
        for (int t16 = 0; t16 < 16; ++t16) {
            int base = (tid * 16 + t16) * 16;
            if (s1[base] < ts[15]) continue;   // sorted desc: skip list
            for (int r2 = 0; r2 < 16; ++r2) {
                float s = s1[base + r2]; int gi = i1[base + r2];
                INS16(s, gi);
            }
        }
#pragma unroll
        for (int r = 0; r < 16; ++r) cand[tid * 16 + r] = ti[r];
    }
    __syncthreads();

    // phase 3: exact fp32 rescore of 256 candidates (wave w: 64 cands)
    {
        const int l = tid & 63, w = tid >> 6;
        float qr[6];
#pragma unroll
        for (int i = 0; i < 6; ++i) qr[i] = qn[q * EMBED + l + 64 * i];
        for (int cc = 0; cc < 64; ++cc) {
            int cd = w * 64 + cc;
            int id = cand[cd];
            const float* dp = docs + (size_t)id * EMBED;
            float dot = 0.f, ss = 0.f;
#pragma unroll
            for (int i = 0; i < 6; ++i) {
                float v = dp[l + 64 * i];
                dot = fmaf(v, qr[i], dot);
                ss = fmaf(v, v, ss);
            }
#pragma unroll
            for (int off = 32; off > 0; off >>= 1) {
                dot += __shfl_xor(dot, off);
                ss  += __shfl_xor(ss, off);
            }
            if (l == 0) {
                float rn = 1.0f / (sqrtf(ss) + EPSN);
                cs2[cd] = dot * rn;
                cn2[cd] = rn;
            }
        }
    }
    __syncthreads();

    // phase 4: exact top-8 of 256, softmax, emit scores+idx
    if (tid == 0) {
        float ts[8]; int ti[8]; int tp[8];
#pragma unroll
        for (int r = 0; r < 8; ++r) { ts[r] = -3.402823466e38f; ti[r] = 0x7fffffff; tp[r] = 0; }
        for (int e = 0; e < 256; ++e) {
            float s = cs2[e]; int id = cand[e];
            if (s > ts[7] || (s == ts[7] && id < ti[7])) {
                ts[7] = s; ti[7] = id; tp[7] = e;
#pragma unroll
                for (int r = 7; r > 0; --r) {
                    bool sw = (ts[r] > ts[r-1]) || (ts[r] == ts[r-1] && ti[r] < ti[r-1]);
                    float a = ts[r-1]; int b = ti[r-1]; int p = tp[r-1];
                    ts[r-1] = sw ? ts[r] : a;  ti[r-1] = sw ? ti[r] : b;  tp[r-1] = sw ? tp[r] : p;
                    ts[r]   = sw ? a : ts[r];  ti[r]   = sw ? b : ti[r];  tp[r]   = sw ? p : tp[r];
                }
            }
        }
        float m = ts[0];
        float wv[8]; float sum = 0.f;
#pragma unroll
        for (int r = 0; r < 8; ++r) { wv[r] = expf(ts[r] - m); sum += wv[r]; }
        float rs = 1.0f / sum;
#pragma unroll
        for (int r = 0; r < 8; ++r) {
            fi[r] = ti[r];
            wr[r] = wv[r] * rs * cn2[tp[r]];   // softmax weight x 1/(||d||+eps)
            out[BATCH * EMBED + q * TOPK + r] = ts[r];
            out[BATCH * EMBED + BATCH * TOPK + q * TOPK + r] = (float)ti[r];
        }
    }
    __syncthreads();

    // phase 5: fused[q][dim] = sum_r wr[r] * docs[fi[r]][dim]
    for (int dim = tid; dim < EMBED; dim += 256) {
        float a = 0.f;
#pragma unroll
        for (int r = 0; r < 8; ++r)
            a += wr[r] * docs[(size_t)fi[r] * EMBED + dim];
        out[q * EMBED + dim] = a;
    }
}

extern "C" void kernel_launch(void* const* d_in, const int* in_sizes, int n_in,
                              void* d_out, int out_size, void* d_ws, size_t ws_size,
                              hipStream_t stream) {
    const float* query = (const float*)d_in[0];
    const float* docs  = (const float*)d_in[1];
    float* out = (float*)d_out;

    char* ws = (char*)d_ws;
    unsigned short* qhf = (unsigned short*)ws;                  // 48 KiB
    float* qn  = (float*)(ws + 49152);                          // 96 KiB
    unsigned short* T = (unsigned short*)(ws + 147456);         // 201.3 MB
    float* pscore = (float*)(ws + 147456 + 201326592ull);       // 4 MiB
    int*   pidx   = (int*)(ws + 147456 + 201326592ull + 4194304ull);

    qprep_kernel<<<64, 64, 0, stream>>>(query, qn, qhf);
    conv_kernel<<<2048, 256, 0, stream>>>(docs, T);
    score_topk_kernel<<<NBLK, 256, 0, stream>>>(T, qhf, pscore, pidx);
    rescore_kernel<<<BATCH, 256, 0, stream>>>(docs, qn, pscore, pidx, out);
}

// Round 11
// 366.090 us; speedup vs baseline: 1.1631x; 1.1631x over previous
//
#include <hip/hip_runtime.h>
#include <math.h>

// NanoRAG: cosine-sim retrieval + top-8 + softmax fusion.
// K0 qprep: normalize queries -> qn fp32 + A-fragment bf16 (qhf)
// K1 fused: 2048 blocks x 256 thr, 128 docs/block as 4x 32-doc tiles.
//   Docs streamed LINEARLY (1KB/wave-instr), rolling half-tile register
//   prefetch with counted vmcnt(6) (never drained), RNE->bf16-hi, shared
//   via XOR-swizzled LDS plane, hi-only MFMA vs 64 q (q-frags persistent
//   in regs), doc norms via mfma(b,b) diagonal, running per-thread top-8
//   -> pscore/pidx [q][2048][8].
// K2 rescore: per query: 16 chunks x approx-top-16 = 256 candidates,
//   exact fp32 rescore + top-8 + softmax + fuse -> d_out. (R10-proven)
//
// d_out layout (fp32): fused[64*384], scores[64*8], idx[64*8]

#define EMBED 384
#define NDOCS 262144
#define BATCH 64
#define TOPK 8
#define NBLK 2048
#define EPSN 1e-8f

typedef __attribute__((ext_vector_type(8))) short bf16x8;
typedef __attribute__((ext_vector_type(4))) float f32x4;

#define INS8(s_, i_) do {                                                     \
    if ((s_) > ts[7] || ((s_) == ts[7] && (i_) < ti[7])) {                    \
        ts[7] = (s_); ti[7] = (i_);                                           \
        _Pragma("unroll")                                                     \
        for (int r_ = 7; r_ > 0; --r_) {                                      \
            bool sw_ = (ts[r_] > ts[r_-1]) ||                                 \
                       (ts[r_] == ts[r_-1] && ti[r_] < ti[r_-1]);             \
            float a_ = ts[r_-1]; int b_ = ti[r_-1];                           \
            ts[r_-1] = sw_ ? ts[r_] : a_;  ti[r_-1] = sw_ ? ti[r_] : b_;      \
            ts[r_]   = sw_ ? a_ : ts[r_];  ti[r_]   = sw_ ? b_ : ti[r_];      \
        }                                                                     \
    }                                                                         \
} while (0)

#define INS16(s_, i_) do {                                                    \
    if ((s_) > ts[15] || ((s_) == ts[15] && (i_) < ti[15])) {                 \
        ts[15] = (s_); ti[15] = (i_);                                         \
        _Pragma("unroll")                                                     \
        for (int r_ = 15; r_ > 0; --r_) {                                     \
            bool sw_ = (ts[r_] > ts[r_-1]) ||                                 \
                       (ts[r_] == ts[r_-1] && ti[r_] < ti[r_-1]);             \
            float a_ = ts[r_-1]; int b_ = ti[r_-1];                           \
            ts[r_-1] = sw_ ? ts[r_] : a_;  ti[r_-1] = sw_ ? ti[r_] : b_;      \
            ts[r_]   = sw_ ? a_ : ts[r_];  ti[r_]   = sw_ ? b_ : ti[r_];      \
        }                                                                     \
    }                                                                         \
} while (0)

// RNE fp32 -> bf16 (manual; proven numerics R2-R10)
__device__ __forceinline__ unsigned rne1(float f) {
    unsigned u = __float_as_uint(f);
    return (u + 0x7fffu + ((u >> 16) & 1u)) >> 16;
}

template<int OFF>
__device__ __forceinline__ int4 gload_s(unsigned voff, const void* sbase) {
    int4 r;
    asm volatile("global_load_dwordx4 %0, %1, %2 offset:%3"
                 : "=v"(r) : "v"(voff), "s"(sbase), "i"(OFF) : "memory");
    return r;
}

// ---------------- K0: query prep (R10-proven) ----------------
__global__ void qprep_kernel(const float* __restrict__ q,
                             float* __restrict__ qn,
                             unsigned short* __restrict__ qhf) {
    const int row = blockIdx.x;     // 64
    const int lane = threadIdx.x;   // 64
    float v[6];
    float s = 0.f;
#pragma unroll
    for (int i = 0; i < 6; ++i) {
        v[i] = q[row * EMBED + lane + 64 * i];
        s = fmaf(v[i], v[i], s);
    }
#pragma unroll
    for (int off = 32; off > 0; off >>= 1) s += __shfl_xor(s, off);
    float rinv = 1.0f / (sqrtf(s) + EPSN);
#pragma unroll
    for (int i = 0; i < 6; ++i) {
        int k = lane + 64 * i;
        float f = v[i] * rinv;
        qn[row * EMBED + k] = f;
        // A-fragment: lane l holds A[row=l&15][k=(l>>4)*8..+7]
        qhf[(row >> 4) * 6144 + (k >> 5) * 512 + ((k >> 3) & 3) * 128
            + (row & 15) * 8 + (k & 7)] = (unsigned short)rne1(f);
    }
}

// ---------------- K1: fused linear-stream score + top-8 ----------------
__global__ __launch_bounds__(256, 3) void score_topk_kernel(
        const float* __restrict__ docs,
        const unsigned short* __restrict__ qhf,
        float* __restrict__ pscore, int* __restrict__ pidx) {
    // LDS: bf16-hi plane 32x768B XOR-swizzled @0 (24576); S[64][33] @24576
    // (8448); RN[32] @33024. Tail overlays Ls@0 / Li@8192 (plane dead).
    __shared__ __align__(16) char smem[33168];
    float* S  = (float*)(smem + 24576);
    float* RN = (float*)(smem + 33024);

    const int tid = threadIdx.x;
    const int l = tid & 63;
    const int w = tid >> 6;            // wave: q-tile for MFMA, quarter for scan
    const int lb15 = l & 15;
    const int d0 = blockIdx.x * 128;

    // persistent q fragments: tile w, all 384 k (48 VGPR)
    int4 qreg[12];
    {
        const unsigned qvb = (unsigned)(w * 12288 + l * 16);
#pragma unroll
        for (int kb = 0; kb < 12; ++kb)
            qreg[kb] = gload_s<0>(qvb + kb * 1024u, qhf);
    }

    // doc stream: chunk F = tid + i*256 (1KB contiguous per wave-instr)
    const unsigned vb = (unsigned)d0 * 1536u + (unsigned)(tid * 16);
    int4 rawA[6], rawB[6];
#pragma unroll
    for (int i = 0; i < 6; ++i) rawA[i] = gload_s<0>(vb + i * 4096u, docs);
#pragma unroll
    for (int i = 0; i < 6; ++i) rawB[i] = gload_s<0>(vb + (i + 6) * 4096u, docs);

    uint2 sh[12];
    unsigned dsw[12];
    float ts[8]; int ti[8];
#pragma unroll
    for (int r = 0; r < 8; ++r) { ts[r] = -3.402823466e38f; ti[r] = 0x7fffffff; }

    const unsigned abase = (unsigned)(lb15 * 768);
    const unsigned key = (unsigned)((l & 7) << 4);
    const unsigned kq16 = (unsigned)((l >> 4) * 16);
    const int sq_ = tid & 63;          // this thread's query for the scan

#define CONV(i, R, ri) {                                                       \
    int F = tid + (i) * 256;                                                   \
    float f0 = __int_as_float(R[ri].x), f1 = __int_as_float(R[ri].y);          \
    float f2 = __int_as_float(R[ri].z), f3 = __int_as_float(R[ri].w);          \
    sh[i].x = rne1(f0) | (rne1(f1) << 16);                                     \
    sh[i].y = rne1(f2) | (rne1(f3) << 16);                                     \
    int dd = (F * 10923) >> 20;        /* F/96, exact for F<3072 */            \
    int r4 = F - dd * 96;                                                      \
    dsw[i] = (unsigned)(dd * 768) + (((unsigned)(r4 * 8)) ^ ((unsigned)((dd & 7) << 4))); \
}

#define KITER(J, LAST) {                                                       \
    asm volatile("s_waitcnt vmcnt(6)" ::: "memory");                           \
    __builtin_amdgcn_sched_barrier(0);                                         \
    _Pragma("unroll")                                                          \
    for (int i = 0; i < 6; ++i) CONV(i, rawA, i);                              \
    if (!(LAST)) {                                                             \
        _Pragma("unroll")                                                      \
        for (int i = 0; i < 6; ++i)                                            \
            rawA[i] = gload_s<0>(vb + ((J) + 1) * 49152u + i * 4096u, docs);   \
    }                                                                          \
    asm volatile("s_waitcnt vmcnt(%0)" :: "i"((LAST) ? 0 : 6) : "memory");     \
    __builtin_amdgcn_sched_barrier(0);                                         \
    _Pragma("unroll")                                                          \
    for (int i = 6; i < 12; ++i) CONV(i, rawB, i - 6);                         \
    if (!(LAST)) {                                                             \
        _Pragma("unroll")                                                      \
        for (int i = 0; i < 6; ++i)                                            \
            rawB[i] = gload_s<0>(vb + ((J) + 1) * 49152u + (i + 6) * 4096u, docs); \
    }                                                                          \
    asm volatile("s_waitcnt lgkmcnt(0)" ::: "memory");                         \
    __builtin_amdgcn_s_barrier();          /* C: prev tile LDS use done */     \
    _Pragma("unroll")                                                          \
    for (int i = 0; i < 12; ++i) *(uint2*)(smem + dsw[i]) = sh[i];             \
    asm volatile("s_waitcnt lgkmcnt(0)" ::: "memory");                         \
    __builtin_amdgcn_s_barrier();          /* A: plane ready */                \
    f32x4 acc0 = (f32x4){0.f,0.f,0.f,0.f}, acc1 = (f32x4){0.f,0.f,0.f,0.f};   \
    f32x4 nrm0 = (f32x4){0.f,0.f,0.f,0.f}, nrm1 = (f32x4){0.f,0.f,0.f,0.f};   \
    _Pragma("unroll")                                                          \
    for (int kb = 0; kb < 12; ++kb) {                                          \
        unsigned ka = ((unsigned)(kb * 64) + kq16) ^ key;                      \
        bf16x8 b0 = *(const bf16x8*)(smem + abase + ka);                       \
        bf16x8 b1 = *(const bf16x8*)(smem + abase + 12288u + ka);              \
        bf16x8 aq = *(const bf16x8*)&qreg[kb];                                 \
        acc0 = __builtin_amdgcn_mfma_f32_16x16x32_bf16(aq, b0, acc0, 0, 0, 0); \
        nrm0 = __builtin_amdgcn_mfma_f32_16x16x32_bf16(b0, b0, nrm0, 0, 0, 0); \
        acc1 = __builtin_amdgcn_mfma_f32_16x16x32_bf16(aq, b1, acc1, 0, 0, 0); \
        nrm1 = __builtin_amdgcn_mfma_f32_16x16x32_bf16(b1, b1, nrm1, 0, 0, 0); \
    }                                                                          \
    if ((l >> 4) == (lb15 >> 2)) {         /* diag lanes: norms */             \
        float n0 = (l & 2) ? ((l & 1) ? nrm0[3] : nrm0[2])                     \
                           : ((l & 1) ? nrm0[1] : nrm0[0]);                    \
        float n1 = (l & 2) ? ((l & 1) ? nrm1[3] : nrm1[2])                     \
                           : ((l & 1) ? nrm1[1] : nrm1[0]);                    \
        RN[lb15] = n0; RN[16 + lb15] = n1;                                     \
    }                                                                          \
    asm volatile("s_waitcnt lgkmcnt(0)" ::: "memory");                         \
    __builtin_amdgcn_s_barrier();          /* A2: RN ready */                  \
    {                                                                          \
        float rn0 = 1.0f / (sqrtf(RN[lb15]) + EPSN);                           \
        float rn1 = 1.0f / (sqrtf(RN[16 + lb15]) + EPSN);                      \
        int row0 = w * 16 + (l >> 4) * 4;                                      \
        _Pragma("unroll")                                                      \
        for (int jj = 0; jj < 4; ++jj) {                                       \
            S[(row0 + jj) * 33 + lb15] = acc0[jj] * rn0;                       \
            S[(row0 + jj) * 33 + 16 + lb15] = acc1[jj] * rn1;                  \
        }                                                                      \
    }                                                                          \
    asm volatile("s_waitcnt lgkmcnt(0)" ::: "memory");                         \
    __builtin_amdgcn_s_barrier();          /* B: S ready */                    \
    _Pragma("unroll")                                                          \
    for (int ii = 0; ii < 8; ++ii) {       /* running top-8, query sq_ */      \
        int dl = w * 8 + ((ii + sq_) & 7);                                     \
        float sc = S[sq_ * 33 + dl];                                           \
        INS8(sc, d0 + (J) * 32 + dl);                                          \
    }                                                                          \
}

    KITER(0, 0) KITER(1, 0) KITER(2, 0) KITER(3, 1)
#undef KITER
#undef CONV

    // tail: merge the 4 quarter lists per query -> pscore[q][block][8]
    asm volatile("s_waitcnt lgkmcnt(0)" ::: "memory");
    __builtin_amdgcn_s_barrier();
    float* Ls = (float*)smem;              // plane dead
    int*   Li = (int*)(smem + 8192);
#pragma unroll
    for (int r = 0; r < 8; ++r) {
        Ls[(w * 64 + sq_) * 8 + r] = ts[r];
        Li[(w * 64 + sq_) * 8 + r] = ti[r];
    }
    asm volatile("s_waitcnt lgkmcnt(0)" ::: "memory");
    __builtin_amdgcn_s_barrier();
    if (tid < 64) {
#pragma unroll
        for (int r = 0; r < 8; ++r) { ts[r] = -3.402823466e38f; ti[r] = 0x7fffffff; }
        for (int a = 0; a < 4; ++a) {
#pragma unroll
            for (int r = 0; r < 8; ++r) {
                float s2 = Ls[(a * 64 + tid) * 8 + r];
                int i2 = Li[(a * 64 + tid) * 8 + r];
                INS8(s2, i2);
            }
        }
        size_t o = ((size_t)tid * NBLK + blockIdx.x) * TOPK;
        *(float4*)&pscore[o]     = make_float4(ts[0], ts[1], ts[2], ts[3]);
        *(float4*)&pscore[o + 4] = make_float4(ts[4], ts[5], ts[6], ts[7]);
        *(int4*)&pidx[o]     = make_int4(ti[0], ti[1], ti[2], ti[3]);
        *(int4*)&pidx[o + 4] = make_int4(ti[4], ti[5], ti[6], ti[7]);
    }
}

// ---------------- K2: candidates + exact rescore + fuse (R10-proven) ------
__global__ __launch_bounds__(256) void rescore_kernel(
        const float* __restrict__ docs, const float* __restrict__ qn,
        const float* __restrict__ pscore, const int* __restrict__ pidx,
        float* __restrict__ out) {
    const int q = blockIdx.x;
    const int tid = threadIdx.x;
    __shared__ float s1[4096];
    __shared__ int   i1[4096];
    __shared__ int   cand[256];
    __shared__ float cs2[256];
    __shared__ float cn2[256];
    __shared__ int   fi[TOPK];
    __shared__ float wr[TOPK];

    // phase 1: 16 chunks x 16 threads; thread scans 64 entries -> top-16
    {
        float ts[16]; int ti[16];
#pragma unroll
        for (int r = 0; r < 16; ++r) { ts[r] = -3.402823466e38f; ti[r] = 0x7fffffff; }
        const int c = tid >> 4, j = tid & 15;
        const float* sp = pscore + (size_t)q * 16384 + c * 1024 + j;
        const int*   ip = pidx   + (size_t)q * 16384 + c * 1024 + j;
        for (int ii = 0; ii < 64; ++ii) {
            float s = sp[ii * 16];
            if (s > ts[15] || (s == ts[15])) {
                int gi = ip[ii * 16];
                INS16(s, gi);
            }
        }
#pragma unroll
        for (int r = 0; r < 16; ++r) { s1[tid * 16 + r] = ts[r]; i1[tid * 16 + r] = ti[r]; }
    }
    __syncthreads();

    // phase 2: one thread per chunk merges its 16 sorted lists -> top-16
    if (tid < 16) {
        float ts[16]; int ti[16];
#pragma unroll
        for (int r = 0; r < 16; ++r) { ts[r] = -3.402823466e38f; ti[r] = 0x7fffffff; }
        for (int t16 = 0; t16 < 16; ++t16) {
            int base = (tid * 16 + t16) * 16;
            if (s1[base] < ts[15]) continue;
            for (int r2 = 0; r2 < 16; ++r2) {
                float s = s1[base + r2]; int gi = i1[base + r2];
                INS16(s, gi);
            }
        }
#pragma unroll
        for (int r = 0; r < 16; ++r) cand[tid * 16 + r] = ti[r];
    }
    __syncthreads();

    // phase 3: exact fp32 rescore of 256 candidates (wave w: 64 cands)
    {
        const int l = tid & 63, w = tid >> 6;
        float qr[6];
#pragma unroll
        for (int i = 0; i < 6; ++i) qr[i] = qn[q * EMBED + l + 64 * i];
        for (int cc = 0; cc < 64; ++cc) {
            int cd = w * 64 + cc;
            int id = cand[cd];
            const float* dp = docs + (size_t)id * EMBED;
            float dot = 0.f, ss = 0.f;
#pragma unroll
            for (int i = 0; i < 6; ++i) {
                float v = dp[l + 64 * i];
                dot = fmaf(v, qr[i], dot);
                ss = fmaf(v, v, ss);
            }
#pragma unroll
            for (int off = 32; off > 0; off >>= 1) {
                dot += __shfl_xor(dot, off);
                ss  += __shfl_xor(ss, off);
            }
            if (l == 0) {
                float rn = 1.0f / (sqrtf(ss) + EPSN);
                cs2[cd] = dot * rn;
                cn2[cd] = rn;
            }
        }
    }
    __syncthreads();

    // phase 4: exact top-8 of 256, softmax, emit scores+idx
    if (tid == 0) {
        float ts[8]; int ti[8]; int tp[8];
#pragma unroll
        for (int r = 0; r < 8; ++r) { ts[r] = -3.402823466e38f; ti[r] = 0x7fffffff; tp[r] = 0; }
        for (int e = 0; e < 256; ++e) {
            float s = cs2[e]; int id = cand[e];
            if (s > ts[7] || (s == ts[7] && id < ti[7])) {
                ts[7] = s; ti[7] = id; tp[7] = e;
#pragma unroll
                for (int r = 7; r > 0; --r) {
                    bool sw = (ts[r] > ts[r-1]) || (ts[r] == ts[r-1] && ti[r] < ti[r-1]);
                    float a = ts[r-1]; int b = ti[r-1]; int p = tp[r-1];
                    ts[r-1] = sw ? ts[r] : a;  ti[r-1] = sw ? ti[r] : b;  tp[r-1] = sw ? tp[r] : p;
                    ts[r]   = sw ? a : ts[r];  ti[r]   = sw ? b : ti[r];  tp[r]   = sw ? p : tp[r];
                }
            }
        }
        float m = ts[0];
        float wv[8]; float sum = 0.f;
#pragma unroll
        for (int r = 0; r < 8; ++r) { wv[r] = expf(ts[r] - m); sum += wv[r]; }
        float rs = 1.0f / sum;
#pragma unroll
        for (int r = 0; r < 8; ++r) {
            fi[r] = ti[r];
            wr[r] = wv[r] * rs * cn2[tp[r]];
            out[BATCH * EMBED + q * TOPK + r] = ts[r];
            out[BATCH * EMBED + BATCH * TOPK + q * TOPK + r] = (float)ti[r];
        }
    }
    __syncthreads();

    // phase 5: fused[q][dim] = sum_r wr[r] * docs[fi[r]][dim]
    for (int dim = tid; dim < EMBED; dim += 256) {
        float a = 0.f;
#pragma unroll
        for (int r = 0; r < 8; ++r)
            a += wr[r] * docs[(size_t)fi[r] * EMBED + dim];
        out[q * EMBED + dim] = a;
    }
}

extern "C" void kernel_launch(void* const* d_in, const int* in_sizes, int n_in,
                              void* d_out, int out_size, void* d_ws, size_t ws_size,
                              hipStream_t stream) {
    const float* query = (const float*)d_in[0];
    const float* docs  = (const float*)d_in[1];
    float* out = (float*)d_out;

    char* ws = (char*)d_ws;
    unsigned short* qhf = (unsigned short*)ws;                  // 48 KiB
    float* qn  = (float*)(ws + 49152);                          // 96 KiB
    float* pscore = (float*)(ws + 147456);                      // 4 MiB
    int*   pidx   = (int*)(ws + 147456 + 4194304ull);           // 4 MiB

    qprep_kernel<<<64, 64, 0, stream>>>(query, qn, qhf);
    score_topk_kernel<<<NBLK, 256, 0, stream>>>(docs, qhf, pscore, pidx);
    rescore_kernel<<<BATCH, 256, 0, stream>>>(docs, qn, pscore, pidx, out);
}